// Round 2
// baseline (1528.208 us; speedup 1.0000x reference)
//
#include <hip/hip_runtime.h>

#define DD 64
#define NPART 8

struct Bounds { int b[7]; };   // internal partition boundaries over global row space

// ---------- single-pass edge partition into 8 destination-range buckets ----------
// Reads each edge once, classifies by destination row range (host-computed,
// expectation-balanced bounds), writes compacted (g, payload) into bucket p via
// block-level LDS ranking: one global atomicAdd per partition per 256-edge chunk,
// ~128B contiguous write runs per bucket per chunk.
__global__ void partition_edges(const int* __restrict__ dA, const int* __restrict__ sA, const int* __restrict__ tA,
                                const int* __restrict__ dB, const int* __restrict__ sB, const int* __restrict__ tB,
                                const int* __restrict__ dC, const int* __restrict__ sC,
                                const int* __restrict__ dD, const int* __restrict__ sD,
                                int nA, int nB, int nC, int nD,
                                int offB, int offC, int offD,
                                Bounds bn, int CAP,
                                int* __restrict__ bcnt, int* __restrict__ bg, int* __restrict__ bp) {
    __shared__ int lcnt[NPART];
    __shared__ int lbase[NPART];
    int t = threadIdx.x;
    int nthr = gridDim.x * blockDim.x;
    int Etot = nA + nB + nC + nD;
    for (int i0 = blockIdx.x * blockDim.x; i0 < Etot; i0 += nthr) {
        int i = i0 + t;
        if (t < NPART) lcnt[t] = 0;
        __syncthreads();
        int g = 0, pv = 0, p = -1, rank = 0;
        if (i < Etot) {
            int j = i;
            if (j < nA)              { g = __builtin_nontemporal_load(dA + j);
                                       pv = __builtin_nontemporal_load(sA + j) | (__builtin_nontemporal_load(tA + j) << 20); }
            else if ((j -= nA) < nB) { g = offB + __builtin_nontemporal_load(dB + j);
                                       pv = __builtin_nontemporal_load(sB + j) | (__builtin_nontemporal_load(tB + j) << 20); }
            else if ((j -= nB) < nC) { g = offC + __builtin_nontemporal_load(dC + j);
                                       pv = __builtin_nontemporal_load(sC + j); }
            else { j -= nC;            g = offD + __builtin_nontemporal_load(dD + j);
                                       pv = __builtin_nontemporal_load(sD + j); }
            p = 0;
#pragma unroll
            for (int q = 0; q < 7; ++q) p += (g >= bn.b[q]);
            rank = atomicAdd(&lcnt[p], 1);
        }
        __syncthreads();
        if (t < NPART) lbase[t] = lcnt[t] ? atomicAdd(&bcnt[t * 16], lcnt[t]) : 0;
        __syncthreads();
        if (p >= 0) {
            int idx = p * CAP + lbase[p] + rank;
            bg[idx] = g;
            bp[idx] = pv;
        }
        __syncthreads();   // protect lcnt reset at top of next iteration
    }
}

// ---------- per-XCD histogram over own bucket (L2-local atomics) ----------
__global__ void hist_p2(const int* __restrict__ bg, const int* __restrict__ bcnt,
                        int CAP, int* __restrict__ counts) {
    int p = blockIdx.x & (NPART - 1);
    int n = bcnt[p * 16];
    int tid = (blockIdx.x >> 3) * blockDim.x + threadIdx.x;
    int nthr = (gridDim.x >> 3) * blockDim.x;
    const int* B = bg + (size_t)p * CAP;
    for (int i = tid; i < n; i += nthr) atomicAdd(&counts[B[i]], 1);
}

// ---------- per-XCD fill: scatter payload into L2-local pay window ----------
__global__ void fill_p2(const int* __restrict__ bg, const int* __restrict__ bp,
                        const int* __restrict__ bcnt, int CAP,
                        int* __restrict__ rowptr, int* __restrict__ pay) {
    int p = blockIdx.x & (NPART - 1);
    int n = bcnt[p * 16];
    int tid = (blockIdx.x >> 3) * blockDim.x + threadIdx.x;
    int nthr = (gridDim.x >> 3) * blockDim.x;
    const int* G = bg + (size_t)p * CAP;
    const int* P = bp + (size_t)p * CAP;
    for (int i = tid; i < n; i += nthr) {
        int g = G[i];
        int pos = atomicAdd(&rowptr[g], 1);
        pay[pos] = P[i];
    }
}

// Exclusive scan, 1024 elems per block (256 thr x 4). In-place safe (reads chunk
// into registers before any write). Per-block totals -> bsums.
__global__ void scan_blocks(const int* in, int* out, int* bsums, int n) {
    __shared__ int ts[256];
    int base = blockIdx.x * 1024;
    int t = threadIdx.x;
    int v[4];
    int loc = 0;
#pragma unroll
    for (int k = 0; k < 4; ++k) {
        int i = base + t * 4 + k;
        v[k] = (i < n) ? in[i] : 0;
        loc += v[k];
    }
    ts[t] = loc;
    __syncthreads();
    for (int off = 1; off < 256; off <<= 1) {
        int x = (t >= off) ? ts[t - off] : 0;
        __syncthreads();
        ts[t] += x;
        __syncthreads();
    }
    if (t == 255) bsums[blockIdx.x] = ts[255];
    int run = (t == 0) ? 0 : ts[t - 1];
#pragma unroll
    for (int k = 0; k < 4; ++k) {
        int i = base + t * 4 + k;
        if (i < n) out[i] = run;
        run += v[k];
    }
}

__global__ void scan_sums(int* __restrict__ bsums, int nb) {
    __shared__ int ts[512];
    int t = threadIdx.x;
    int v = (t < nb) ? bsums[t] : 0;
    ts[t] = v;
    __syncthreads();
    for (int off = 1; off < 512; off <<= 1) {
        int x = (t >= off) ? ts[t - off] : 0;
        __syncthreads();
        ts[t] += x;
        __syncthreads();
    }
    if (t < nb) bsums[t] = ts[t] - v;   // exclusive
}

__global__ void add_offsets(int* __restrict__ out, const int* __restrict__ bsums, int n) {
    int i = blockIdx.x * blockDim.x + threadIdx.x;
    if (i < n) out[i] += bsums[i >> 10];
}

// ---------- combined gather-reduce ----------
// One wave per destination row. Payload broadcast via v_readlane -> SGPR; decode
// on SALU; loads are uniform-base + lane-offset so address arith leaves the VALU.
__global__ void gather_all(const float* __restrict__ entity_emb,
                           const float* __restrict__ user_emb,
                           const float* __restrict__ weight,
                           const int* __restrict__ rowptr, const int* __restrict__ pay,
                           float* __restrict__ out, float* __restrict__ usr_out,
                           float* __restrict__ iu, float* __restrict__ ui,
                           int offB, int offC, int offD, int n_rows) {
    int w = blockIdx.x * (blockDim.x >> 6) + (threadIdx.x >> 6);
    int lane = threadIdx.x & 63;
    if (w >= n_rows) return;

    const float* emb;
    float* dst;
    if (w < offB)      { int r = w;        emb = entity_emb; dst = out     + ((size_t)r * DD); }
    else if (w < offC) { int r = w - offB; emb = user_emb;   dst = usr_out + ((size_t)r * DD); }
    else if (w < offD) { int r = w - offC; emb = user_emb;   dst = iu      + ((size_t)r * DD); }
    else               { int r = w - offD; emb = entity_emb; dst = ui      + ((size_t)r * DD); }

    int start = (w == 0) ? 0 : rowptr[w - 1];
    int end = rowptr[w];
    float acc = 0.f;
    for (int base = start; base < end; base += 64) {
        int m = end - base; if (m > 64) m = 64;
        int pv = (lane < m) ? pay[base + lane] : 0;
        int j = 0;
        for (; j + 4 <= m; j += 4) {
            int p0 = __builtin_amdgcn_readlane(pv, j);
            int p1 = __builtin_amdgcn_readlane(pv, j + 1);
            int p2 = __builtin_amdgcn_readlane(pv, j + 2);
            int p3 = __builtin_amdgcn_readlane(pv, j + 3);
            float e0 = emb[((p0 & 0xFFFFF) << 6) + lane];
            float w0 = weight[((p0 >> 20) << 6) + lane];
            float e1 = emb[((p1 & 0xFFFFF) << 6) + lane];
            float w1 = weight[((p1 >> 20) << 6) + lane];
            float e2 = emb[((p2 & 0xFFFFF) << 6) + lane];
            float w2 = weight[((p2 >> 20) << 6) + lane];
            float e3 = emb[((p3 & 0xFFFFF) << 6) + lane];
            float w3 = weight[((p3 >> 20) << 6) + lane];
            acc += e0 * w0; acc += e1 * w1; acc += e2 * w2; acc += e3 * w3;
        }
        for (; j < m; ++j) {
            int pj = __builtin_amdgcn_readlane(pv, j);
            acc += emb[((pj & 0xFFFFF) << 6) + lane] * weight[((pj >> 20) << 6) + lane];
        }
    }
    int deg = end - start;
    dst[lane] = acc / (float)(deg > 0 ? deg : 1);
}

// ---------- gated fusion (in-place on a_ == out is safe: per-element RAW only) ----------
__global__ void gate_fuse_kernel(const float* a_, const float* b_,
                                 const float* __restrict__ gA, const float* __restrict__ gB,
                                 float* out, int n_rows) {
    __shared__ float GA[DD][DD + 1];   // GA[k][d] = gA[d][k]
    __shared__ float GB[DD][DD + 1];
    for (int i = threadIdx.x; i < DD * DD; i += blockDim.x) {
        int d = i >> 6, k = i & 63;
        GA[k][d] = gA[i];
        GB[k][d] = gB[i];
    }
    __syncthreads();
    int lane = threadIdx.x & 63;
    int waves_per_blk = blockDim.x >> 6;
    int row0 = blockIdx.x * waves_per_blk + (threadIdx.x >> 6);
    int stride = gridDim.x * waves_per_blk;
    for (int row = row0; row < n_rows; row += stride) {
        float a = a_[(size_t)row * DD + lane];
        float b = b_[(size_t)row * DD + lane];
        float z = 0.f;
#pragma unroll
        for (int k = 0; k < DD; ++k) {
            float ak = __shfl(a, k, 64);
            float bk = __shfl(b, k, 64);
            z += ak * GA[k][lane] + bk * GB[k][lane];
        }
        float g = 1.f / (1.f + expf(-z));
        out[(size_t)row * DD + lane] = g * a + (1.f - g) * b;
    }
}

extern "C" void kernel_launch(void* const* d_in, const int* in_sizes, int n_in,
                              void* d_out, int out_size, void* d_ws, size_t ws_size,
                              hipStream_t stream) {
    const float* entity_emb = (const float*)d_in[0];
    const float* user_emb   = (const float*)d_in[1];
    const float* weight     = (const float*)d_in[2];
    const float* g1         = (const float*)d_in[3];
    const float* g2         = (const float*)d_in[4];
    const float* g3         = (const float*)d_in[5];
    const int* edge_index  = (const int*)d_in[6];   // (2,E): row0=head(dst), row1=tail(src)
    const int* edge_type   = (const int*)d_in[7];
    const int* uedge_index = (const int*)d_in[8];   // (2,UE)
    const int* uedge_type  = (const int*)d_in[9];
    const int* mat_row     = (const int*)d_in[10];  // user ids
    const int* mat_col     = (const int*)d_in[11];  // item ids

    const int n_entities   = in_sizes[0] / DD;  // 180000
    const int n_user_nodes = in_sizes[1] / DD;  // 150000
    const int nA           = in_sizes[7];       // 1500000 entity edges
    const int nB           = in_sizes[9];       // 1000000 user edges
    const int nM           = in_sizes[10];      // 1500000 interaction edges
    const int n_items      = 50000;
    const int n_users      = 100000;

    const int offB = n_entities;                // 180000
    const int offC = offB + n_user_nodes;       // 330000
    const int offD = offC + n_items;            // 380000
    const int R    = offD + n_users;            // 480000 total rows
    const int Etot = nA + nB + nM + nM;         // 5.5M edges
    const int CAP  = Etot / NPART + 16384;      // bucket capacity (>>20 sigma slack)

    float* out      = (float*)d_out;
    float* user_out = out + (size_t)n_entities * DD;

    // workspace (~69 MB): ints, then iu/ui alias the bucket region (dead by gather)
    int* ibase  = (int*)d_ws;
    int* counts = ibase;                     // R (scanned in place -> rowptr)
    int* bsums  = ibase + R;                 // 512
    int* bcnt   = ibase + R + 512;           // 8*16 (padded cursors)
    int* pay    = ibase + R + 512 + 128;     // Etot
    int* bg     = pay + Etot;                // 8*CAP
    int* bp     = bg + (size_t)NPART * CAP;  // 8*CAP
    float* iu   = (float*)bg;                // 50k*64 floats  \ fit in 16*CAP ints
    float* ui   = iu + (size_t)n_items * DD; // 100k*64 floats /

    // expectation-balanced partition bounds over row space (piecewise-linear invert)
    Bounds bn;
    {
        double cum[5]  = {0.0, (double)nA, (double)nA + nB, (double)nA + nB + nM,
                          (double)nA + nB + 2.0 * nM};
        int    segS[4] = {0, offB, offC, offD};
        int    segR[4] = {n_entities, n_user_nodes, n_items, n_users};
        for (int p = 1; p < NPART; ++p) {
            double T = cum[4] * p / NPART;
            int s = 0;
            while (s < 3 && T >= cum[s + 1]) ++s;
            double frac = (T - cum[s]) / (cum[s + 1] - cum[s]);
            bn.b[p - 1] = segS[s] + (int)(frac * segR[s]);
        }
    }

    hipMemsetAsync(counts, 0, (size_t)(R + 512 + 128) * sizeof(int), stream);

    partition_edges<<<2048, 256, 0, stream>>>(edge_index, edge_index + nA, edge_type,
                                              uedge_index, uedge_index + nB, uedge_type,
                                              mat_col, mat_row,
                                              mat_row, mat_col,
                                              nA, nB, nM, nM, offB, offC, offD,
                                              bn, CAP, bcnt, bg, bp);
    hist_p2<<<NPART * 512, 256, 0, stream>>>(bg, bcnt, CAP, counts);
    int nb = (R + 1023) / 1024;   // 469 <= 512
    scan_blocks<<<nb, 256, 0, stream>>>(counts, counts, bsums, R);
    scan_sums<<<1, 512, 0, stream>>>(bsums, nb);
    add_offsets<<<(R + 255) / 256, 256, 0, stream>>>(counts, bsums, R);
    fill_p2<<<NPART * 512, 256, 0, stream>>>(bg, bp, bcnt, CAP, counts, pay);
    gather_all<<<(R + 3) / 4, 256, 0, stream>>>(entity_emb, user_emb, weight,
                                                counts, pay,
                                                out, user_out, iu, ui,
                                                offB, offC, offD, R);

    // items: gi = sig(kg@g1.T + iu@g2.T); out = gi*kg + (1-gi)*iu   (kg in-place in out)
    gate_fuse_kernel<<<1024, 256, 0, stream>>>(out, iu, g1, g2, out, n_items);
    // users: hi = sig(ui@g2.T + ukg@g3.T); out = hi*ukg + (1-hi)*ui (ukg in-place)
    gate_fuse_kernel<<<2048, 256, 0, stream>>>(user_out, ui, g3, g2, user_out, n_users);
}

// Round 3
// 709.895 us; speedup vs baseline: 2.1527x; 2.1527x over previous
//
#include <hip/hip_runtime.h>

#define DD 64
#define NBKT 512
#define CHUNK 8192
#define CAP_B 13312   // bucket capacity in edges (mean 10.7K, ~24 sigma slack)

struct SegCfg {
    int qbase[4];   // first bucket id of segment
    int rpb[4];     // rows per bucket
    float inv[4];   // 1.f / rpb
    int soff[4];    // global row offset of segment
    int rows[4];    // rows in segment
};

// ---------- K1: 512-way multisplit with dense, full-line bucket writes ----------
// Each block owns one 8192-edge chunk: decode + classify, LDS rank (count/scan),
// reorder into a 64KB LDS buffer so each bucket's elements are contiguous, then
// stream each run (mean 16 edges = 128B) to its global bucket cursor. No sparse
// global stores anywhere.
__global__ void __launch_bounds__(512, 2)
split_kernel(const int* __restrict__ dA, const int* __restrict__ sA, const int* __restrict__ tA,
             const int* __restrict__ dB, const int* __restrict__ sB, const int* __restrict__ tB,
             const int* __restrict__ dC, const int* __restrict__ sC,
             const int* __restrict__ dD, const int* __restrict__ sD,
             int nA, int nB, int nC, int nD,
             SegCfg cfg, int* __restrict__ gcur, unsigned long long* __restrict__ bkt) {
    __shared__ unsigned long long ord[CHUNK];   // 64 KB
    __shared__ int cnt[NBKT];
    __shared__ int sc[NBKT];
    __shared__ int gb[NBKT];
    int t = threadIdx.x;
    int Etot = nA + nB + nC + nD;
    int base = blockIdx.x * CHUNK;
    if (base >= Etot) return;

    cnt[t] = 0;
    __syncthreads();

    unsigned long long val[16];
    int qv[16], rv[16];
#pragma unroll
    for (int k = 0; k < 16; ++k) {
        int i = base + k * 512 + t;
        qv[k] = -1;
        if (i < Etot) {
            int j = i, d, seg, pv;
            if (j < nA)              { seg = 0; d = dA[j]; pv = sA[j] | (tA[j] << 20); }
            else if ((j -= nA) < nB) { seg = 1; d = dB[j]; pv = sB[j] | (tB[j] << 20); }
            else if ((j -= nB) < nC) { seg = 2; d = dC[j]; pv = sC[j]; }
            else { j -= nC;            seg = 3; d = dD[j]; pv = sD[j]; }
            int rpb = cfg.rpb[seg];
            int q = (int)((float)d * cfg.inv[seg]);
            if (d >= (q + 1) * rpb) ++q;
            else if (d < q * rpb) --q;
            int g = d + cfg.soff[seg];
            val[k] = ((unsigned long long)g << 25) | (unsigned)pv;
            qv[k] = q + cfg.qbase[seg];
            rv[k] = atomicAdd(&cnt[qv[k]], 1);
        }
    }
    __syncthreads();

    // exclusive scan of cnt -> sc; per-bucket global cursor -> gb
    {
        int v = cnt[t];
        sc[t] = v;
        __syncthreads();
        for (int off = 1; off < NBKT; off <<= 1) {
            int y = (t >= off) ? sc[t - off] : 0;
            __syncthreads();
            sc[t] += y;
            __syncthreads();
        }
        sc[t] -= v;   // exclusive
        gb[t] = (v > 0) ? atomicAdd(&gcur[t], v) : 0;
    }
    __syncthreads();

#pragma unroll
    for (int k = 0; k < 16; ++k)
        if (qv[k] >= 0) ord[sc[qv[k]] + rv[k]] = val[k];
    __syncthreads();

    // streamout: wave w handles buckets w, w+8, ...; contiguous full-line runs
    int wv = t >> 6, lane = t & 63;
    for (int q = wv; q < NBKT; q += 8) {
        int len = cnt[q];
        if (!len) continue;
        int s0 = sc[q];
        unsigned long long* dst = bkt + (size_t)q * CAP_B + gb[q];
        for (int l = lane; l < len; l += 64) dst[l] = ord[s0 + l];
    }
}

// exclusive scan of 512 bucket counts -> pay bases (keeps counts intact)
__global__ void scan512(const int* __restrict__ in, int* __restrict__ out) {
    __shared__ int ts[512];
    int t = threadIdx.x;
    int v = in[t];
    ts[t] = v;
    __syncthreads();
    for (int off = 1; off < 512; off <<= 1) {
        int y = (t >= off) ? ts[t - off] : 0;
        __syncthreads();
        ts[t] += y;
        __syncthreads();
    }
    out[t] = ts[t] - v;
}

// ---------- K2: per-bucket LDS counting sort -> rowptr + sorted pay ----------
// One block per bucket. Histogram rows in LDS, scan, write rowptr densely,
// scatter payloads into LDS stage, stream out full lines. Replaces
// hist + scan_blocks + add_offsets + scatter-fill with zero sparse stores.
__global__ void __launch_bounds__(512, 2)
bucket_sort_kernel(const unsigned long long* __restrict__ bkt,
                   const int* __restrict__ gcur, const int* __restrict__ pbase,
                   SegCfg cfg, int* __restrict__ rowptr, int* __restrict__ pay) {
    __shared__ int cnt[2048];
    __shared__ int part[512];
    __shared__ int stage[CAP_B];   // 53 KB
    int b = blockIdx.x, t = threadIdx.x;

    int seg = 0;
    if (b >= cfg.qbase[3]) seg = 3;
    else if (b >= cfg.qbase[2]) seg = 2;
    else if (b >= cfg.qbase[1]) seg = 1;
    int lb = b - cfg.qbase[seg];
    int row0 = cfg.soff[seg] + lb * cfg.rpb[seg];
    int nr = cfg.rows[seg] - lb * cfg.rpb[seg];
    if (nr > cfg.rpb[seg]) nr = cfg.rpb[seg];
    int n = gcur[b];
    int base = pbase[b];
    const unsigned long long* src = bkt + (size_t)b * CAP_B;

    for (int i = t; i < 2048; i += 512) cnt[i] = 0;
    __syncthreads();
    for (int i = t; i < n; i += 512) {
        int g = (int)(src[i] >> 25);
        atomicAdd(&cnt[g - row0], 1);
    }
    __syncthreads();

    // exclusive scan of cnt[0..2048): 4 elems/thread + scan of partials
    {
        int s = 0;
#pragma unroll
        for (int k = 0; k < 4; ++k) s += cnt[t * 4 + k];
        part[t] = s;
        __syncthreads();
        for (int off = 1; off < 512; off <<= 1) {
            int y = (t >= off) ? part[t - off] : 0;
            __syncthreads();
            part[t] += y;
            __syncthreads();
        }
        int run = part[t] - s;
#pragma unroll
        for (int k = 0; k < 4; ++k) { int c = cnt[t * 4 + k]; cnt[t * 4 + k] = run; run += c; }
    }
    __syncthreads();

    // rowptr[g] = END position of row g (global); dense write
    for (int r = t; r < nr; r += 512)
        rowptr[row0 + r] = base + cnt[r + 1];   // cnt[nr..] stayed == n
    __syncthreads();

    // scatter into LDS stage via row cursors (cnt holds exclusive starts)
    for (int i = t; i < n; i += 512) {
        unsigned long long v = src[i];
        int g = (int)(v >> 25);
        int pos = atomicAdd(&cnt[g - row0], 1);
        stage[pos] = (int)(v & 0x1FFFFFF);
    }
    __syncthreads();
    for (int i = t; i < n; i += 512)
        pay[base + i] = stage[i];
}

// ---------- combined gather-reduce (unchanged) ----------
__global__ void gather_all(const float* __restrict__ entity_emb,
                           const float* __restrict__ user_emb,
                           const float* __restrict__ weight,
                           const int* __restrict__ rowptr, const int* __restrict__ pay,
                           float* __restrict__ out, float* __restrict__ usr_out,
                           float* __restrict__ iu, float* __restrict__ ui,
                           int offB, int offC, int offD, int n_rows) {
    int w = blockIdx.x * (blockDim.x >> 6) + (threadIdx.x >> 6);
    int lane = threadIdx.x & 63;
    if (w >= n_rows) return;

    const float* emb;
    float* dst;
    if (w < offB)      { int r = w;        emb = entity_emb; dst = out     + ((size_t)r * DD); }
    else if (w < offC) { int r = w - offB; emb = user_emb;   dst = usr_out + ((size_t)r * DD); }
    else if (w < offD) { int r = w - offC; emb = user_emb;   dst = iu      + ((size_t)r * DD); }
    else               { int r = w - offD; emb = entity_emb; dst = ui      + ((size_t)r * DD); }

    int start = (w == 0) ? 0 : rowptr[w - 1];
    int end = rowptr[w];
    float acc = 0.f;
    for (int base = start; base < end; base += 64) {
        int m = end - base; if (m > 64) m = 64;
        int pv = (lane < m) ? pay[base + lane] : 0;
        int j = 0;
        for (; j + 4 <= m; j += 4) {
            int p0 = __builtin_amdgcn_readlane(pv, j);
            int p1 = __builtin_amdgcn_readlane(pv, j + 1);
            int p2 = __builtin_amdgcn_readlane(pv, j + 2);
            int p3 = __builtin_amdgcn_readlane(pv, j + 3);
            float e0 = emb[((p0 & 0xFFFFF) << 6) + lane];
            float w0 = weight[((p0 >> 20) << 6) + lane];
            float e1 = emb[((p1 & 0xFFFFF) << 6) + lane];
            float w1 = weight[((p1 >> 20) << 6) + lane];
            float e2 = emb[((p2 & 0xFFFFF) << 6) + lane];
            float w2 = weight[((p2 >> 20) << 6) + lane];
            float e3 = emb[((p3 & 0xFFFFF) << 6) + lane];
            float w3 = weight[((p3 >> 20) << 6) + lane];
            acc += e0 * w0; acc += e1 * w1; acc += e2 * w2; acc += e3 * w3;
        }
        for (; j < m; ++j) {
            int pj = __builtin_amdgcn_readlane(pv, j);
            acc += emb[((pj & 0xFFFFF) << 6) + lane] * weight[((pj >> 20) << 6) + lane];
        }
    }
    int deg = end - start;
    dst[lane] = acc / (float)(deg > 0 ? deg : 1);
}

// ---------- gated fusion (in-place safe: per-element RAW only) ----------
__global__ void gate_fuse_kernel(const float* a_, const float* b_,
                                 const float* __restrict__ gA, const float* __restrict__ gB,
                                 float* out, int n_rows) {
    __shared__ float GA[DD][DD + 1];
    __shared__ float GB[DD][DD + 1];
    for (int i = threadIdx.x; i < DD * DD; i += blockDim.x) {
        int d = i >> 6, k = i & 63;
        GA[k][d] = gA[i];
        GB[k][d] = gB[i];
    }
    __syncthreads();
    int lane = threadIdx.x & 63;
    int waves_per_blk = blockDim.x >> 6;
    int row0 = blockIdx.x * waves_per_blk + (threadIdx.x >> 6);
    int stride = gridDim.x * waves_per_blk;
    for (int row = row0; row < n_rows; row += stride) {
        float a = a_[(size_t)row * DD + lane];
        float b = b_[(size_t)row * DD + lane];
        float z = 0.f;
#pragma unroll
        for (int k = 0; k < DD; ++k) {
            float ak = __shfl(a, k, 64);
            float bk = __shfl(b, k, 64);
            z += ak * GA[k][lane] + bk * GB[k][lane];
        }
        float g = 1.f / (1.f + expf(-z));
        out[(size_t)row * DD + lane] = g * a + (1.f - g) * b;
    }
}

extern "C" void kernel_launch(void* const* d_in, const int* in_sizes, int n_in,
                              void* d_out, int out_size, void* d_ws, size_t ws_size,
                              hipStream_t stream) {
    const float* entity_emb = (const float*)d_in[0];
    const float* user_emb   = (const float*)d_in[1];
    const float* weight     = (const float*)d_in[2];
    const float* g1         = (const float*)d_in[3];
    const float* g2         = (const float*)d_in[4];
    const float* g3         = (const float*)d_in[5];
    const int* edge_index  = (const int*)d_in[6];
    const int* edge_type   = (const int*)d_in[7];
    const int* uedge_index = (const int*)d_in[8];
    const int* uedge_type  = (const int*)d_in[9];
    const int* mat_row     = (const int*)d_in[10];
    const int* mat_col     = (const int*)d_in[11];

    const int n_entities   = in_sizes[0] / DD;  // 180000
    const int n_user_nodes = in_sizes[1] / DD;  // 150000
    const int nA           = in_sizes[7];       // 1500000
    const int nB           = in_sizes[9];       // 1000000
    const int nM           = in_sizes[10];      // 1500000
    const int n_items      = 50000;
    const int n_users      = 100000;

    const int offB = n_entities;                // 180000
    const int offC = offB + n_user_nodes;       // 330000
    const int offD = offC + n_items;            // 380000
    const int R    = offD + n_users;            // 480000
    const int Etot = nA + nB + nM + nM;         // 5.5M

    float* out      = (float*)d_out;
    float* user_out = out + (size_t)n_entities * DD;

    // workspace (~78 MB): buckets first (8B aligned), iu/ui overlay buckets
    unsigned long long* bkt = (unsigned long long*)d_ws;        // NBKT*CAP_B*8 = 54.5 MB
    int* ia     = (int*)(bkt + (size_t)NBKT * CAP_B);
    int* rowptr = ia;               // R
    int* gcur   = ia + R;           // 512
    int* pbase  = ia + R + 512;     // 512
    int* pay    = ia + R + 1024;    // Etot
    float* iu   = (float*)bkt;                   // 50k*64 f32 (buckets dead by gather)
    float* ui   = iu + (size_t)n_items * DD;     // 100k*64 f32

    // expectation-balanced bucket layout
    SegCfg cfg;
    {
        int nb[4];
        nb[0] = (int)((long long)nA * NBKT / Etot);
        nb[1] = (int)((long long)nB * NBKT / Etot);
        nb[2] = (int)((long long)nM * NBKT / Etot);
        nb[3] = NBKT - nb[0] - nb[1] - nb[2];
        int rows[4] = {n_entities, n_user_nodes, n_items, n_users};
        int soff[4] = {0, offB, offC, offD};
        int qb = 0;
        for (int s = 0; s < 4; ++s) {
            cfg.qbase[s] = qb;
            cfg.rpb[s]   = (rows[s] + nb[s] - 1) / nb[s];
            cfg.inv[s]   = 1.0f / (float)cfg.rpb[s];
            cfg.soff[s]  = soff[s];
            cfg.rows[s]  = rows[s];
            qb += nb[s];
        }
    }

    hipMemsetAsync(gcur, 0, 512 * sizeof(int), stream);

    int nchunk = (Etot + CHUNK - 1) / CHUNK;    // 672
    split_kernel<<<nchunk, 512, 0, stream>>>(edge_index, edge_index + nA, edge_type,
                                             uedge_index, uedge_index + nB, uedge_type,
                                             mat_col, mat_row,
                                             mat_row, mat_col,
                                             nA, nB, nM, nM, cfg, gcur, bkt);
    scan512<<<1, 512, 0, stream>>>(gcur, pbase);
    bucket_sort_kernel<<<NBKT, 512, 0, stream>>>(bkt, gcur, pbase, cfg, rowptr, pay);
    gather_all<<<(R + 3) / 4, 256, 0, stream>>>(entity_emb, user_emb, weight,
                                                rowptr, pay,
                                                out, user_out, iu, ui,
                                                offB, offC, offD, R);

    gate_fuse_kernel<<<1024, 256, 0, stream>>>(out, iu, g1, g2, out, n_items);
    gate_fuse_kernel<<<2048, 256, 0, stream>>>(user_out, ui, g3, g2, user_out, n_users);
}